// Round 8
// baseline (78.106 us; speedup 1.0000x reference)
//
#include <hip/hip_runtime.h>
#include <stdint.h>

#define NB 4
#define NC 256
#define NH 60
#define NW 80
#define NN (NH*NW)   // 4800

#define M_POS 1.0f
#define M_NEG 0.2f
#define THR2  64.0f  // THRESHOLD^2

typedef __attribute__((ext_vector_type(4))) float f32x4;
typedef __attribute__((ext_vector_type(8))) int   i32x8;
typedef __attribute__((ext_vector_type(4))) int   i32x4v;

#define SC1 0x7F7F7F7F   // e8m0 scale bytes = 127 -> 2^0 = 1.0

// ws layout (bytes):
//      0 : gemmbuf[6000] float
//  24000 : corrbuf[4800] float     (contiguous: NPART = 10800 floats from 0)
// 102400 : A8 [B][N][C] fp8 e4m3   (4915200 B)
// 5017600: B8 [B][N][C] fp8 e4m3   (4915200 B)
#define CORR_OFF 24000
#define A8_OFF   102400
#define B8_OFF   5017600
#define NPART    10800

#define NGEMM 6000
#define NCORR 4800

// ---------------- transpose+convert [C][N] f32 -> [N][C] fp8 ----------------
__global__ void t8_kernel(const float* __restrict__ da, const float* __restrict__ db,
                          unsigned char* __restrict__ A8, unsigned char* __restrict__ B8) {
  int t = blockIdx.x;              // 0..2399 = 2 tensors * 4 b * 4 ct * 75 nt
  int tensor = t / 1200; int rem = t % 1200;
  int b  = rem / 300;    int rem2 = rem % 300;
  int ct = rem2 / 75,    nt = rem2 % 75;
  int c0 = ct * 64, n0 = nt * 64;
  const float* in = (tensor ? db : da) + ((size_t)b * NC + c0) * NN + n0;
  unsigned char* out = (tensor ? B8 : A8) + ((size_t)b * NN + n0) * NC + c0;

  __shared__ float tile[64][65];
  int tr = threadIdx.x >> 6, tc = threadIdx.x & 63;
  #pragma unroll
  for (int i = 0; i < 16; ++i) {
    int c = i * 4 + tr;
    tile[c][tc] = in[(size_t)c * NN + tc];
  }
  __syncthreads();
  // each thread: one n-row, 16 consecutive channels -> one uint4 store
  int n_loc = threadIdx.x >> 2;        // 0..63
  int cb    = (threadIdx.x & 3) * 16;  // 0,16,32,48
  uint32_t wv[4];
  #pragma unroll
  for (int q = 0; q < 4; ++q) {
    uint32_t r = 0;
    r = __builtin_amdgcn_cvt_pk_fp8_f32(tile[cb + q*4 + 0][n_loc], tile[cb + q*4 + 1][n_loc], r, 0);
    r = __builtin_amdgcn_cvt_pk_fp8_f32(tile[cb + q*4 + 2][n_loc], tile[cb + q*4 + 3][n_loc], r, 1);
    wv[q] = r;
  }
  uint4 pack = make_uint4(wv[0], wv[1], wv[2], wv[3]);
  *(uint4*)&out[(size_t)n_loc * NC + cb] = pack;
}

__device__ __forceinline__ float fp8_to_f32(uint32_t v8) {
  uint32_t s = (v8 >> 7) & 1u, e = (v8 >> 3) & 15u, m = v8 & 7u;
  float r;
  if (e) {
    r = __uint_as_float((s << 31) | ((e + 120u) << 23) | (m << 20));
  } else {
    r = (float)(int)m * 0.001953125f;   // 2^-9
    r = s ? -r : r;
  }
  return r;
}

// ---------------- fused MX-fp8 GEMM(+hinge) + corr kernel ----------------
// blocks [0,6000): GEMM 160(n)x96(m), 4 waves 2x2, wave 80x48 = 5x3 frags,
//                  mfma_scale 16x16x128 fp8, K=256 = 2 chained MFMAs, scale=1
//                  single-stage: whole K-tile in 64KB LDS, one barrier
// blocks [6000,10800): sparse mask correction (4 waves = 4 (b,n) items)
#define BM 160
#define BN 96

__global__ __launch_bounds__(256, 2) void fused_kernel(
    const unsigned char* __restrict__ A8, const unsigned char* __restrict__ B8,
    const float* __restrict__ H,
    float* __restrict__ gemmbuf, float* __restrict__ corrbuf) {
  __shared__ unsigned char smem[65536];   // [0,40960)=A 160x256, [40960,65536)=B 96x256
  float* red = (float*)smem;              // aliased after compute (barrier-guarded)

  int bid = blockIdx.x;
  int tid = threadIdx.x;
  int w = tid >> 6, l = tid & 63;

  if (bid >= NGEMM) {
    // ================= corr path (fp8 inputs, inline decode) =================
    int cb  = bid - NGEMM;                 // 0..4799
    int gid = cb * 4 + w;                  // 0..19199
    int b = gid / NN, n = gid % NN;
    int gi = n / NW, gj = n % NW;
    float x = gj * 8.0f + 4.0f, y = gi * 8.0f + 4.0f;
    const float* h = H + b * 9;
    float inv = 1.0f / (h[6] * x + h[7] * y + h[8]);
    float wx = (h[0] * x + h[1] * y + h[2]) * inv;
    float wy = (h[3] * x + h[4] * y + h[5]) * inv;

    const uint32_t av = *(const uint32_t*)(A8 + (size_t)(b * NN + n) * NC + l * 4);
    float a0 = fp8_to_f32(av), a1 = fp8_to_f32(av >> 8);
    float a2 = fp8_to_f32(av >> 16), a3 = fp8_to_f32(av >> 24);

    float fy = fminf(fmaxf((wy - 4.0f) * 0.125f, -2.0f), (float)NH + 1.0f);
    float fx = fminf(fmaxf((wx - 4.0f) * 0.125f, -2.0f), (float)NW + 1.0f);
    int i0 = (int)floorf(fy), j0 = (int)floorf(fx);

    bool  val[4];
    float dot[4];
    #pragma unroll
    for (int c = 0; c < 4; ++c) {
      int im = i0 + (c >> 1), jm = j0 + (c & 1);
      float dx = wx - (jm * 8.0f + 4.0f);
      float dy = wy - (im * 8.0f + 4.0f);
      bool v = (im >= 0) & (im < NH) & (jm >= 0) & (jm < NW) &
               (dx * dx + dy * dy <= THR2);
      val[c] = v;
      int m = v ? (im * NW + jm) : 0;
      const uint32_t bv = *(const uint32_t*)(B8 + (size_t)(b * NN + m) * NC + l * 4);
      dot[c] = a0 * fp8_to_f32(bv)       + a1 * fp8_to_f32(bv >> 8)
             + a2 * fp8_to_f32(bv >> 16) + a3 * fp8_to_f32(bv >> 24);
    }
    #pragma unroll
    for (int off = 32; off > 0; off >>= 1) {
      dot[0] += __shfl_xor(dot[0], off);
      dot[1] += __shfl_xor(dot[1], off);
      dot[2] += __shfl_xor(dot[2], off);
      dot[3] += __shfl_xor(dot[3], off);
    }
    float corr = 0.0f;
    #pragma unroll
    for (int c = 0; c < 4; ++c)
      if (val[c])
        corr += fmaxf(M_POS - dot[c], 0.0f) - fmaxf(dot[c] - M_NEG, 0.0f);
    if (l == 0) red[w] = corr;
    __syncthreads();
    if (tid == 0) corrbuf[cb] = red[0] + red[1] + red[2] + red[3];
    return;
  }

  // ================= GEMM path =================
  // XCD-aware bijective swizzle over the 6000 gemm blocks
  int nb = (bid & 7) * 750 + (bid >> 3);
  int b = nb / 1500; int r = nb % 1500;
  int tn = r / 50, tm = r % 50;
  int n0 = tn * BM, m0 = tm * BN;
  int wr = w >> 1, wc = w & 1;

  const unsigned char* Ab = A8 + (size_t)b * NN * NC;
  const unsigned char* Bb = B8 + (size_t)b * NN * NC;

  // ---- stage whole 160x256 A + 96x256 B (fp8) into LDS
  // 4096 chunks of 16B; linear LDS dest, XOR-involution on SOURCE:
  // scol = col ^ (row & 15)  (16 x 16B columns per 256B row)
  #pragma unroll
  for (int it = 0; it < 16; ++it) {
    int cid = it * 256 + tid;
    if (cid < 2560) {
      int row = cid >> 4, col = cid & 15;
      int scol = col ^ (row & 15);
      __builtin_amdgcn_global_load_lds(
          (const __attribute__((address_space(1))) uint32_t*)(Ab + (size_t)(n0 + row) * NC + scol * 16),
          (__attribute__((address_space(3))) uint32_t*)(&smem[cid * 16]), 16, 0, 0);
    } else {
      int cid2 = cid - 2560;
      int row = cid2 >> 4, col = cid2 & 15;
      int scol = col ^ (row & 15);
      __builtin_amdgcn_global_load_lds(
          (const __attribute__((address_space(1))) uint32_t*)(Bb + (size_t)(m0 + row) * NC + scol * 16),
          (__attribute__((address_space(3))) uint32_t*)(&smem[40960 + cid2 * 16]), 16, 0, 0);
    }
  }
  __syncthreads();   // vmcnt(0) drain + barrier: tile resident

  f32x4 acc[5][3];
  #pragma unroll
  for (int i = 0; i < 5; ++i)
    #pragma unroll
    for (int j = 0; j < 3; ++j)
      acc[i][j] = (f32x4){0.f, 0.f, 0.f, 0.f};

  // ---- compute: 2 K-blocks of 128, 15 mfma_scale each
  // fragment: lane group g=l>>4 holds k-bytes [kb*128 + g*32, +32) =
  // 16B cols {kb*8+2g, kb*8+2g+1}, XOR-swizzled per row (same involution)
  #pragma unroll
  for (int kb = 0; kb < 2; ++kb) {
    int c0 = kb * 8 + ((l >> 4) << 1);
    i32x8 Af[5], Bf[3];
    #pragma unroll
    for (int i = 0; i < 5; ++i) {
      int ra = wr * 80 + i * 16 + (l & 15);
      const unsigned char* base = &smem[ra * 256];
      i32x4v lo = *(const i32x4v*)(base + ((c0)     ^ (ra & 15)) * 16);
      i32x4v hi = *(const i32x4v*)(base + ((c0 + 1) ^ (ra & 15)) * 16);
      Af[i] = __builtin_shufflevector(lo, hi, 0, 1, 2, 3, 4, 5, 6, 7);
    }
    #pragma unroll
    for (int j = 0; j < 3; ++j) {
      int rb = wc * 48 + j * 16 + (l & 15);
      const unsigned char* base = &smem[40960 + rb * 256];
      i32x4v lo = *(const i32x4v*)(base + ((c0)     ^ (rb & 15)) * 16);
      i32x4v hi = *(const i32x4v*)(base + ((c0 + 1) ^ (rb & 15)) * 16);
      Bf[j] = __builtin_shufflevector(lo, hi, 0, 1, 2, 3, 4, 5, 6, 7);
    }
    __builtin_amdgcn_s_setprio(1);
    #pragma unroll
    for (int i = 0; i < 5; ++i)
      #pragma unroll
      for (int j = 0; j < 3; ++j)
        acc[i][j] = __builtin_amdgcn_mfma_scale_f32_16x16x128_f8f6f4(
            Af[i], Bf[j], acc[i][j], 0, 0, 0, SC1, 0, SC1);
    __builtin_amdgcn_s_setprio(0);
  }

  // ---- epilogue: negative-branch hinge only (mask handled by corr path)
  float lsum = 0.0f;
  #pragma unroll
  for (int i = 0; i < 5; ++i)
    #pragma unroll
    for (int j = 0; j < 3; ++j)
      #pragma unroll
      for (int q = 0; q < 4; ++q)
        lsum += fmaxf(acc[i][j][q] - M_NEG, 0.0f);

  #pragma unroll
  for (int off = 32; off > 0; off >>= 1)
    lsum += __shfl_xor(lsum, off);

  __syncthreads();                // all waves done reading smem (red aliases it)
  if (l == 0) red[w] = lsum;
  __syncthreads();
  if (tid == 0)
    gemmbuf[nb] = red[0] + red[1] + red[2] + red[3];
}

// ---------------- final reduction over all partials ----------------
__global__ void finalize_kernel(const float* __restrict__ parts, float* __restrict__ out) {
  float v = 0.0f;
  for (int i = threadIdx.x; i < NPART; i += 1024)
    v += parts[i];
  #pragma unroll
  for (int off = 32; off > 0; off >>= 1)
    v += __shfl_xor(v, off);
  __shared__ float red[16];
  if ((threadIdx.x & 63) == 0) red[threadIdx.x >> 6] = v;
  __syncthreads();
  if (threadIdx.x == 0) {
    float s = 0.0f;
    #pragma unroll
    for (int i = 0; i < 16; ++i) s += red[i];
    out[0] = s * (1.0f / ((float)NB * (float)NN * (float)NN));
  }
}

extern "C" void kernel_launch(void* const* d_in, const int* in_sizes, int n_in,
                              void* d_out, int out_size, void* d_ws, size_t ws_size,
                              hipStream_t stream) {
  const float* da = (const float*)d_in[0];
  const float* db = (const float*)d_in[1];
  const float* H  = (const float*)d_in[2];
  // d_in[3] = valid_mask (all ones, unused by the reference math)

  char* ws = (char*)d_ws;
  float* gemmbuf = (float*)ws;                    // 6000 floats
  float* corrbuf = (float*)(ws + CORR_OFF);       // 4800 floats, contiguous after
  unsigned char* A8 = (unsigned char*)(ws + A8_OFF);
  unsigned char* B8 = (unsigned char*)(ws + B8_OFF);

  t8_kernel<<<2400, 256, 0, stream>>>(da, db, A8, B8);
  fused_kernel<<<NGEMM + NCORR, 256, 0, stream>>>(A8, B8, H, gemmbuf, corrbuf);
  finalize_kernel<<<1, 1024, 0, stream>>>(gemmbuf, (float*)d_out);
}

// Round 9
// 72.642 us; speedup vs baseline: 1.0752x; 1.0752x over previous
//
#include <hip/hip_runtime.h>
#include <stdint.h>

#define NB 4
#define NC 256
#define NH 60
#define NW 80
#define NN (NH*NW)   // 4800

#define M_POS 1.0f
#define M_NEG 0.2f
#define THR2  64.0f  // THRESHOLD^2

typedef __attribute__((ext_vector_type(4))) float f32x4;

// ws layout (bytes):
//      0 : gemmbuf[6000] float
//  24000 : corrbuf[4800] float     (contiguous: NPART = 10800 floats from 0)
// 102400 : A8 [B][N][C] fp8 e4m3   (4915200 B)
// 5017600: B8 [B][N][C] fp8 e4m3   (4915200 B)
#define CORR_OFF 24000
#define A8_OFF   102400
#define B8_OFF   5017600
#define NPART    10800

#define NGEMM 6000
#define NCORR 4800

// ---------------- transpose+convert [C][N] f32 -> [N][C] fp8 ----------------
__global__ void t8_kernel(const float* __restrict__ da, const float* __restrict__ db,
                          unsigned char* __restrict__ A8, unsigned char* __restrict__ B8) {
  int t = blockIdx.x;              // 0..2399 = 2 tensors * 4 b * 4 ct * 75 nt
  int tensor = t / 1200; int rem = t % 1200;
  int b  = rem / 300;    int rem2 = rem % 300;
  int ct = rem2 / 75,    nt = rem2 % 75;
  int c0 = ct * 64, n0 = nt * 64;
  const float* in = (tensor ? db : da) + ((size_t)b * NC + c0) * NN + n0;
  unsigned char* out = (tensor ? B8 : A8) + ((size_t)b * NN + n0) * NC + c0;

  __shared__ float tile[64][65];
  int tr = threadIdx.x >> 6, tc = threadIdx.x & 63;
  #pragma unroll
  for (int i = 0; i < 16; ++i) {
    int c = i * 4 + tr;
    tile[c][tc] = in[(size_t)c * NN + tc];
  }
  __syncthreads();
  // each thread: one n-row, 16 consecutive channels -> one uint4 store
  int n_loc = threadIdx.x >> 2;        // 0..63
  int cb    = (threadIdx.x & 3) * 16;  // 0,16,32,48
  uint32_t wv[4];
  #pragma unroll
  for (int q = 0; q < 4; ++q) {
    uint32_t r = 0;
    r = __builtin_amdgcn_cvt_pk_fp8_f32(tile[cb + q*4 + 0][n_loc], tile[cb + q*4 + 1][n_loc], r, 0);
    r = __builtin_amdgcn_cvt_pk_fp8_f32(tile[cb + q*4 + 2][n_loc], tile[cb + q*4 + 3][n_loc], r, 1);
    wv[q] = r;
  }
  uint4 pack = make_uint4(wv[0], wv[1], wv[2], wv[3]);
  *(uint4*)&out[(size_t)n_loc * NC + cb] = pack;
}

__device__ __forceinline__ float fp8_to_f32(uint32_t v8) {
  uint32_t s = (v8 >> 7) & 1u, e = (v8 >> 3) & 15u, m = v8 & 7u;
  float r;
  if (e) {
    r = __uint_as_float((s << 31) | ((e + 120u) << 23) | (m << 20));
  } else {
    r = (float)(int)m * 0.001953125f;   // 2^-9
    r = s ? -r : r;
  }
  return r;
}

// ---------------- fused fp8 GEMM(+hinge) + corr kernel ----------------
// blocks [0,6000): GEMM 160(n)x96(m), 4 waves 2x2, wave 80x48 = 5x3 frags,
//   mfma_f32_16x16x32_fp8_fp8, K=256 in 4 chunks of BK=64 (16KB/chunk),
//   3 LDS buffers, counted vmcnt(4), 1 barrier per chunk  (R6 structure)
// blocks [6000,10800): sparse mask correction (4 waves = 4 (b,n) items)
#define BM 160
#define BN 96
#define BK 64

// 1024 16B-chunks per stage: 0..639 = A (160 rows x 4 cols), 640..1023 = B (96x4)
// 4 global_load_lds per thread. linear LDS dest; XOR-involution on SOURCE:
// scol = col ^ ((row>>1)&3)   (16B columns within the 64B row)
#define STAGE(kb, LA, LB) do {                                                        \
    _Pragma("unroll")                                                                 \
    for (int i_ = 0; i_ < 4; ++i_) {                                                  \
      if (inA_[i_])                                                                   \
        __builtin_amdgcn_global_load_lds(                                             \
            (const __attribute__((address_space(1))) uint32_t*)(gsrc_[i_] + (kb) * BK), \
            (__attribute__((address_space(3))) uint32_t*)(&LA[ldso_[i_]]), 16, 0, 0); \
      else                                                                            \
        __builtin_amdgcn_global_load_lds(                                             \
            (const __attribute__((address_space(1))) uint32_t*)(gsrc_[i_] + (kb) * BK), \
            (__attribute__((address_space(3))) uint32_t*)(&LB[ldso_[i_]]), 16, 0, 0); \
    }                                                                                 \
  } while (0)

// 2 k-steps of 32; frag = 8 fp8 bytes (ds_read_b64); k-step toggles offset^32
#define COMPUTE(LA, LB) do {                                                          \
    _Pragma("unroll")                                                                 \
    for (int s_ = 0; s_ < 2; ++s_) {                                                  \
      long af_[5], bf_[3];                                                            \
      _Pragma("unroll")                                                               \
      for (int i_ = 0; i_ < 5; ++i_)                                                  \
        af_[i_] = *(const long*)&LA[aoff_[i_] ^ (s_ * 32)];                           \
      _Pragma("unroll")                                                               \
      for (int j_ = 0; j_ < 3; ++j_)                                                  \
        bf_[j_] = *(const long*)&LB[boff_[j_] ^ (s_ * 32)];                           \
      __builtin_amdgcn_s_setprio(1);                                                  \
      _Pragma("unroll")                                                               \
      for (int i_ = 0; i_ < 5; ++i_)                                                  \
        _Pragma("unroll")                                                             \
        for (int j_ = 0; j_ < 3; ++j_)                                                \
          acc[i_][j_] = __builtin_amdgcn_mfma_f32_16x16x32_fp8_fp8(af_[i_], bf_[j_],  \
                                                                   acc[i_][j_], 0, 0, 0); \
      __builtin_amdgcn_s_setprio(0);                                                  \
    }                                                                                 \
  } while (0)

// counted-vmcnt wait + raw barrier; memory clobber + sched fence (rule #18)
#define WAITV_BAR(N) do {                                              \
    asm volatile("s_waitcnt vmcnt(" #N ")" ::: "memory");              \
    __builtin_amdgcn_sched_barrier(0);                                 \
    __builtin_amdgcn_s_barrier();                                      \
    __builtin_amdgcn_sched_barrier(0);                                 \
  } while (0)

__global__ __launch_bounds__(256, 3) void fused_kernel(
    const unsigned char* __restrict__ A8, const unsigned char* __restrict__ B8,
    const float* __restrict__ H,
    float* __restrict__ gemmbuf, float* __restrict__ corrbuf) {
  __shared__ unsigned char la0[BM * BK], la1[BM * BK], la2[BM * BK];
  __shared__ unsigned char lb0[BN * BK], lb1[BN * BK], lb2[BN * BK];
  __shared__ float red[4];

  int bid = blockIdx.x;
  int tid = threadIdx.x;
  int w = tid >> 6, l = tid & 63;

  if (bid >= NGEMM) {
    // ================= corr path (fp8 inputs, inline decode) =================
    int cb  = bid - NGEMM;                 // 0..4799
    int gid = cb * 4 + w;                  // 0..19199
    int b = gid / NN, n = gid % NN;
    int gi = n / NW, gj = n % NW;
    float x = gj * 8.0f + 4.0f, y = gi * 8.0f + 4.0f;
    const float* h = H + b * 9;
    float inv = 1.0f / (h[6] * x + h[7] * y + h[8]);
    float wx = (h[0] * x + h[1] * y + h[2]) * inv;
    float wy = (h[3] * x + h[4] * y + h[5]) * inv;

    const uint32_t av = *(const uint32_t*)(A8 + (size_t)(b * NN + n) * NC + l * 4);
    float a0 = fp8_to_f32(av), a1 = fp8_to_f32(av >> 8);
    float a2 = fp8_to_f32(av >> 16), a3 = fp8_to_f32(av >> 24);

    float fy = fminf(fmaxf((wy - 4.0f) * 0.125f, -2.0f), (float)NH + 1.0f);
    float fx = fminf(fmaxf((wx - 4.0f) * 0.125f, -2.0f), (float)NW + 1.0f);
    int i0 = (int)floorf(fy), j0 = (int)floorf(fx);

    bool  val[4];
    float dot[4];
    #pragma unroll
    for (int c = 0; c < 4; ++c) {
      int im = i0 + (c >> 1), jm = j0 + (c & 1);
      float dx = wx - (jm * 8.0f + 4.0f);
      float dy = wy - (im * 8.0f + 4.0f);
      bool v = (im >= 0) & (im < NH) & (jm >= 0) & (jm < NW) &
               (dx * dx + dy * dy <= THR2);
      val[c] = v;
      int m = v ? (im * NW + jm) : 0;
      const uint32_t bv = *(const uint32_t*)(B8 + (size_t)(b * NN + m) * NC + l * 4);
      dot[c] = a0 * fp8_to_f32(bv)       + a1 * fp8_to_f32(bv >> 8)
             + a2 * fp8_to_f32(bv >> 16) + a3 * fp8_to_f32(bv >> 24);
    }
    #pragma unroll
    for (int off = 32; off > 0; off >>= 1) {
      dot[0] += __shfl_xor(dot[0], off);
      dot[1] += __shfl_xor(dot[1], off);
      dot[2] += __shfl_xor(dot[2], off);
      dot[3] += __shfl_xor(dot[3], off);
    }
    float corr = 0.0f;
    #pragma unroll
    for (int c = 0; c < 4; ++c)
      if (val[c])
        corr += fmaxf(M_POS - dot[c], 0.0f) - fmaxf(dot[c] - M_NEG, 0.0f);
    if (l == 0) red[w] = corr;
    __syncthreads();
    if (tid == 0) corrbuf[cb] = red[0] + red[1] + red[2] + red[3];
    return;
  }

  // ================= GEMM path =================
  // XCD-aware bijective swizzle over the 6000 gemm blocks
  int nb = (bid & 7) * 750 + (bid >> 3);
  int b = nb / 1500; int r = nb % 1500;
  int tn = r / 50, tm = r % 50;
  int n0 = tn * BM, m0 = tm * BN;
  int wr = w >> 1, wc = w & 1;

  const unsigned char* Ab = A8 + (size_t)b * NN * NC;
  const unsigned char* Bb = B8 + (size_t)b * NN * NC;

  // hoisted staging addresses (loop-invariant; kb*64B folds into imm offset)
  bool inA_[4]; const unsigned char* gsrc_[4]; int ldso_[4];
  #pragma unroll
  for (int i = 0; i < 4; ++i) {
    int base = w * 256 + i * 64;
    int cid = base + l;
    if (base < 640) {
      int row = cid >> 2, col = cid & 3;
      int scol = col ^ ((row >> 1) & 3);
      inA_[i] = true;
      gsrc_[i] = Ab + (size_t)(n0 + row) * NC + scol * 16;
      ldso_[i] = base * 16;
    } else {
      int cid2 = cid - 640;
      int row = cid2 >> 2, col = cid2 & 3;
      int scol = col ^ ((row >> 1) & 3);
      inA_[i] = false;
      gsrc_[i] = Bb + (size_t)(m0 + row) * NC + scol * 16;
      ldso_[i] = (base - 640) * 16;
    }
  }
  // hoisted LDS fragment byte-offsets (same involution on READ):
  // col8' = g ^ (((row>>1)&3)<<1); k-step 1 = offset ^ 32
  int aoff_[5], boff_[3];
  {
    int g = l >> 4;
    #pragma unroll
    for (int i = 0; i < 5; ++i) {
      int ra = wr * 80 + i * 16 + (l & 15);
      aoff_[i] = ra * 64 + ((g ^ (((ra >> 1) & 3) << 1)) << 3);
    }
    #pragma unroll
    for (int j = 0; j < 3; ++j) {
      int rb = wc * 48 + j * 16 + (l & 15);
      boff_[j] = rb * 64 + ((g ^ (((rb >> 1) & 3) << 1)) << 3);
    }
  }

  f32x4 acc[5][3];
  #pragma unroll
  for (int i = 0; i < 5; ++i)
    #pragma unroll
    for (int j = 0; j < 3; ++j)
      acc[i][j] = (f32x4){0.f, 0.f, 0.f, 0.f};

  // 4-chunk, 3-buffer rotation, prefetch-2, counted vmcnt
  STAGE(0, la0, lb0);
  STAGE(1, la1, lb1);
  WAITV_BAR(4);                                    // chunk 0 landed
  STAGE(2, la2, lb2); COMPUTE(la0, lb0); WAITV_BAR(4);   // chunk 1 landed
  STAGE(3, la0, lb0); COMPUTE(la1, lb1); WAITV_BAR(4);   // chunk 2 landed
  COMPUTE(la2, lb2);  WAITV_BAR(0);                      // chunk 3 landed (drain)
  COMPUTE(la0, lb0);

  // epilogue: negative-branch hinge only (mask handled by corr path)
  float lsum = 0.0f;
  #pragma unroll
  for (int i = 0; i < 5; ++i)
    #pragma unroll
    for (int j = 0; j < 3; ++j)
      #pragma unroll
      for (int q = 0; q < 4; ++q)
        lsum += fmaxf(acc[i][j][q] - M_NEG, 0.0f);

  #pragma unroll
  for (int off = 32; off > 0; off >>= 1)
    lsum += __shfl_xor(lsum, off);
  if (l == 0) red[w] = lsum;
  __syncthreads();
  if (tid == 0)
    gemmbuf[nb] = red[0] + red[1] + red[2] + red[3];
}

// ---------------- final reduction over all partials ----------------
__global__ void finalize_kernel(const float* __restrict__ parts, float* __restrict__ out) {
  float v = 0.0f;
  for (int i = threadIdx.x; i < NPART; i += 1024)
    v += parts[i];
  #pragma unroll
  for (int off = 32; off > 0; off >>= 1)
    v += __shfl_xor(v, off);
  __shared__ float red[16];
  if ((threadIdx.x & 63) == 0) red[threadIdx.x >> 6] = v;
  __syncthreads();
  if (threadIdx.x == 0) {
    float s = 0.0f;
    #pragma unroll
    for (int i = 0; i < 16; ++i) s += red[i];
    out[0] = s * (1.0f / ((float)NB * (float)NN * (float)NN));
  }
}

extern "C" void kernel_launch(void* const* d_in, const int* in_sizes, int n_in,
                              void* d_out, int out_size, void* d_ws, size_t ws_size,
                              hipStream_t stream) {
  const float* da = (const float*)d_in[0];
  const float* db = (const float*)d_in[1];
  const float* H  = (const float*)d_in[2];
  // d_in[3] = valid_mask (all ones, unused by the reference math)

  char* ws = (char*)d_ws;
  float* gemmbuf = (float*)ws;                    // 6000 floats
  float* corrbuf = (float*)(ws + CORR_OFF);       // 4800 floats, contiguous after
  unsigned char* A8 = (unsigned char*)(ws + A8_OFF);
  unsigned char* B8 = (unsigned char*)(ws + B8_OFF);

  t8_kernel<<<2400, 256, 0, stream>>>(da, db, A8, B8);
  fused_kernel<<<NGEMM + NCORR, 256, 0, stream>>>(A8, B8, H, gemmbuf, corrbuf);
  finalize_kernel<<<1, 1024, 0, stream>>>(gemmbuf, (float*)d_out);
}

// Round 10
// 58.665 us; speedup vs baseline: 1.3314x; 1.2382x over previous
//
#include <hip/hip_runtime.h>
#include <stdint.h>

#define NB 4
#define NC 256
#define NH 60
#define NW 80
#define NN (NH*NW)   // 4800

#define M_POS 1.0f
#define M_NEG 0.2f
#define THR2  64.0f  // THRESHOLD^2

typedef __attribute__((ext_vector_type(4))) float f32x4;
typedef __attribute__((ext_vector_type(2))) long i64x2;

// ws layout (bytes):
//      0 : gemmbuf[6000] float
//  24000 : corrbuf[4800] float     (contiguous: NPART = 10800 floats from 0)
// 102400 : A8 [B][N][C] fp8 e4m3   (4915200 B)
// 5017600: B8 [B][N][C] fp8 e4m3   (4915200 B)
#define CORR_OFF 24000
#define A8_OFF   102400
#define B8_OFF   5017600
#define NPART    10800

#define NGEMM 6000
#define NCORR 4800

// ---------------- transpose+convert [C][N] f32 -> [N][C] fp8 ----------------
__global__ void t8_kernel(const float* __restrict__ da, const float* __restrict__ db,
                          unsigned char* __restrict__ A8, unsigned char* __restrict__ B8) {
  int t = blockIdx.x;              // 0..2399 = 2 tensors * 4 b * 4 ct * 75 nt
  int tensor = t / 1200; int rem = t % 1200;
  int b  = rem / 300;    int rem2 = rem % 300;
  int ct = rem2 / 75,    nt = rem2 % 75;
  int c0 = ct * 64, n0 = nt * 64;
  const float* in = (tensor ? db : da) + ((size_t)b * NC + c0) * NN + n0;
  unsigned char* out = (tensor ? B8 : A8) + ((size_t)b * NN + n0) * NC + c0;

  __shared__ float tile[64][65];
  int tr = threadIdx.x >> 6, tc = threadIdx.x & 63;
  #pragma unroll
  for (int i = 0; i < 16; ++i) {
    int c = i * 4 + tr;
    tile[c][tc] = in[(size_t)c * NN + tc];
  }
  __syncthreads();
  // each thread: one n-row, 16 consecutive channels -> one uint4 store
  int n_loc = threadIdx.x >> 2;        // 0..63
  int cb    = (threadIdx.x & 3) * 16;  // 0,16,32,48
  uint32_t wv[4];
  #pragma unroll
  for (int q = 0; q < 4; ++q) {
    uint32_t r = 0;
    r = __builtin_amdgcn_cvt_pk_fp8_f32(tile[cb + q*4 + 0][n_loc], tile[cb + q*4 + 1][n_loc], r, 0);
    r = __builtin_amdgcn_cvt_pk_fp8_f32(tile[cb + q*4 + 2][n_loc], tile[cb + q*4 + 3][n_loc], r, 1);
    wv[q] = r;
  }
  uint4 pack = make_uint4(wv[0], wv[1], wv[2], wv[3]);
  *(uint4*)&out[(size_t)n_loc * NC + cb] = pack;
}

// ---------------- fused fp8 GEMM(+hinge) + corr kernel ----------------
// blocks [0,6000): GEMM 160(n)x96(m), 4 waves 2x2, wave 80x48 = 5x3 frags,
//   mfma_f32_16x16x32_fp8_fp8, K=256 in 4 chunks of BK=64 (16KB/chunk),
//   3 LDS buffers, counted vmcnt(4), 1 barrier per chunk.
//   Frag reads = ds_read_b128 (both k-steps at once; lo/hi 8B halves feed
//   MFMA calls 0/1 -- identical k-permutation on A and B => exact).
// blocks [6000,10800): sparse mask correction (4 waves = 4 (b,n) items)
#define BM 160
#define BN 96
#define BK 64

// 1024 16B-chunks per stage: 0..639 = A (160 rows x 4 cols), 640..1023 = B (96x4)
// 4 global_load_lds per thread. linear LDS dest; XOR-involution on SOURCE:
// scol = col ^ ((row>>1)&3)   (16B columns within the 64B row)
#define STAGE(kb, LA, LB) do {                                                        \
    _Pragma("unroll")                                                                 \
    for (int i_ = 0; i_ < 4; ++i_) {                                                  \
      if (inA_[i_])                                                                   \
        __builtin_amdgcn_global_load_lds(                                             \
            (const __attribute__((address_space(1))) uint32_t*)(gsrc_[i_] + (kb) * BK), \
            (__attribute__((address_space(3))) uint32_t*)(&LA[ldso_[i_]]), 16, 0, 0); \
      else                                                                            \
        __builtin_amdgcn_global_load_lds(                                             \
            (const __attribute__((address_space(1))) uint32_t*)(gsrc_[i_] + (kb) * BK), \
            (__attribute__((address_space(3))) uint32_t*)(&LB[ldso_[i_]]), 16, 0, 0); \
    }                                                                                 \
  } while (0)

// 8 x ds_read_b128 (conflict-free: 16B cols, per-row XOR bijection), then
// 15 MFMA on lo halves (k-perm group 0) + 15 on hi halves (group 1)
#define COMPUTE(LA, LB) do {                                                          \
    i64x2 av_[5], bv_[3];                                                             \
    _Pragma("unroll")                                                                 \
    for (int i_ = 0; i_ < 5; ++i_) av_[i_] = *(const i64x2*)&LA[aoff_[i_]];           \
    _Pragma("unroll")                                                                 \
    for (int j_ = 0; j_ < 3; ++j_) bv_[j_] = *(const i64x2*)&LB[boff_[j_]];           \
    __builtin_amdgcn_s_setprio(1);                                                    \
    _Pragma("unroll")                                                                 \
    for (int i_ = 0; i_ < 5; ++i_)                                                    \
      _Pragma("unroll")                                                               \
      for (int j_ = 0; j_ < 3; ++j_)                                                  \
        acc[i_][j_] = __builtin_amdgcn_mfma_f32_16x16x32_fp8_fp8(av_[i_][0], bv_[j_][0], \
                                                                 acc[i_][j_], 0, 0, 0); \
    _Pragma("unroll")                                                                 \
    for (int i_ = 0; i_ < 5; ++i_)                                                    \
      _Pragma("unroll")                                                               \
      for (int j_ = 0; j_ < 3; ++j_)                                                  \
        acc[i_][j_] = __builtin_amdgcn_mfma_f32_16x16x32_fp8_fp8(av_[i_][1], bv_[j_][1], \
                                                                 acc[i_][j_], 0, 0, 0); \
    __builtin_amdgcn_s_setprio(0);                                                    \
  } while (0)

// counted-vmcnt wait + raw barrier; memory clobber + sched fence (rule #18)
#define WAITV_BAR(N) do {                                              \
    asm volatile("s_waitcnt vmcnt(" #N ")" ::: "memory");              \
    __builtin_amdgcn_sched_barrier(0);                                 \
    __builtin_amdgcn_s_barrier();                                      \
    __builtin_amdgcn_sched_barrier(0);                                 \
  } while (0)

__global__ __launch_bounds__(256, 3) void fused_kernel(
    const unsigned char* __restrict__ A8, const unsigned char* __restrict__ B8,
    const float* __restrict__ H,
    float* __restrict__ gemmbuf, float* __restrict__ corrbuf) {
  __shared__ unsigned char la0[BM * BK], la1[BM * BK], la2[BM * BK];
  __shared__ unsigned char lb0[BN * BK], lb1[BN * BK], lb2[BN * BK];
  __shared__ float red[4];

  int bid = blockIdx.x;
  int tid = threadIdx.x;
  int w = tid >> 6, l = tid & 63;

  if (bid >= NGEMM) {
    // ================= corr path (fp8 inputs, HW cvt) =================
    int cb  = bid - NGEMM;                 // 0..4799
    int gid = cb * 4 + w;                  // 0..19199
    int b = gid / NN, n = gid % NN;
    int gi = n / NW, gj = n % NW;
    float x = gj * 8.0f + 4.0f, y = gi * 8.0f + 4.0f;
    const float* h = H + b * 9;
    float inv = 1.0f / (h[6] * x + h[7] * y + h[8]);
    float wx = (h[0] * x + h[1] * y + h[2]) * inv;
    float wy = (h[3] * x + h[4] * y + h[5]) * inv;

    const uint32_t av = *(const uint32_t*)(A8 + (size_t)(b * NN + n) * NC + l * 4);
    float a0 = __builtin_amdgcn_cvt_f32_fp8(av, 0);
    float a1 = __builtin_amdgcn_cvt_f32_fp8(av, 1);
    float a2 = __builtin_amdgcn_cvt_f32_fp8(av, 2);
    float a3 = __builtin_amdgcn_cvt_f32_fp8(av, 3);

    float fy = fminf(fmaxf((wy - 4.0f) * 0.125f, -2.0f), (float)NH + 1.0f);
    float fx = fminf(fmaxf((wx - 4.0f) * 0.125f, -2.0f), (float)NW + 1.0f);
    int i0 = (int)floorf(fy), j0 = (int)floorf(fx);

    bool  val[4];
    float dot[4];
    #pragma unroll
    for (int c = 0; c < 4; ++c) {
      int im = i0 + (c >> 1), jm = j0 + (c & 1);
      float dx = wx - (jm * 8.0f + 4.0f);
      float dy = wy - (im * 8.0f + 4.0f);
      bool v = (im >= 0) & (im < NH) & (jm >= 0) & (jm < NW) &
               (dx * dx + dy * dy <= THR2);
      val[c] = v;
      int m = v ? (im * NW + jm) : 0;
      const uint32_t bv = *(const uint32_t*)(B8 + (size_t)(b * NN + m) * NC + l * 4);
      dot[c] = a0 * __builtin_amdgcn_cvt_f32_fp8(bv, 0)
             + a1 * __builtin_amdgcn_cvt_f32_fp8(bv, 1)
             + a2 * __builtin_amdgcn_cvt_f32_fp8(bv, 2)
             + a3 * __builtin_amdgcn_cvt_f32_fp8(bv, 3);
    }
    #pragma unroll
    for (int off = 32; off > 0; off >>= 1) {
      dot[0] += __shfl_xor(dot[0], off);
      dot[1] += __shfl_xor(dot[1], off);
      dot[2] += __shfl_xor(dot[2], off);
      dot[3] += __shfl_xor(dot[3], off);
    }
    float corr = 0.0f;
    #pragma unroll
    for (int c = 0; c < 4; ++c)
      if (val[c])
        corr += fmaxf(M_POS - dot[c], 0.0f) - fmaxf(dot[c] - M_NEG, 0.0f);
    if (l == 0) red[w] = corr;
    __syncthreads();
    if (tid == 0) corrbuf[cb] = red[0] + red[1] + red[2] + red[3];
    return;
  }

  // ================= GEMM path =================
  // XCD-aware bijective swizzle over the 6000 gemm blocks
  int nb = (bid & 7) * 750 + (bid >> 3);
  int b = nb / 1500; int r = nb % 1500;
  int tn = r / 50, tm = r % 50;
  int n0 = tn * BM, m0 = tm * BN;
  int wr = w >> 1, wc = w & 1;

  const unsigned char* Ab = A8 + (size_t)b * NN * NC;
  const unsigned char* Bb = B8 + (size_t)b * NN * NC;

  // hoisted staging addresses (loop-invariant; kb*64B folds into imm offset)
  bool inA_[4]; const unsigned char* gsrc_[4]; int ldso_[4];
  #pragma unroll
  for (int i = 0; i < 4; ++i) {
    int base = w * 256 + i * 64;
    int cid = base + l;
    if (base < 640) {
      int row = cid >> 2, col = cid & 3;
      int scol = col ^ ((row >> 1) & 3);
      inA_[i] = true;
      gsrc_[i] = Ab + (size_t)(n0 + row) * NC + scol * 16;
      ldso_[i] = base * 16;
    } else {
      int cid2 = cid - 640;
      int row = cid2 >> 2, col = cid2 & 3;
      int scol = col ^ ((row >> 1) & 3);
      inA_[i] = false;
      gsrc_[i] = Bb + (size_t)(m0 + row) * NC + scol * 16;
      ldso_[i] = (base - 640) * 16;
    }
  }
  // hoisted LDS fragment byte-offsets: b128 at 16B col (g16 ^ ((row>>1)&3))
  int aoff_[5], boff_[3];
  {
    int g16 = l >> 4;   // 0..3
    #pragma unroll
    for (int i = 0; i < 5; ++i) {
      int ra = wr * 80 + i * 16 + (l & 15);
      aoff_[i] = ra * 64 + ((g16 ^ ((ra >> 1) & 3)) << 4);
    }
    #pragma unroll
    for (int j = 0; j < 3; ++j) {
      int rb = wc * 48 + j * 16 + (l & 15);
      boff_[j] = rb * 64 + ((g16 ^ ((rb >> 1) & 3)) << 4);
    }
  }

  f32x4 acc[5][3];
  #pragma unroll
  for (int i = 0; i < 5; ++i)
    #pragma unroll
    for (int j = 0; j < 3; ++j)
      acc[i][j] = (f32x4){0.f, 0.f, 0.f, 0.f};

  // 4-chunk, 3-buffer rotation, prefetch-2, counted vmcnt
  STAGE(0, la0, lb0);
  STAGE(1, la1, lb1);
  WAITV_BAR(4);                                    // chunk 0 landed
  STAGE(2, la2, lb2); COMPUTE(la0, lb0); WAITV_BAR(4);   // chunk 1 landed
  STAGE(3, la0, lb0); COMPUTE(la1, lb1); WAITV_BAR(4);   // chunk 2 landed
  COMPUTE(la2, lb2);  WAITV_BAR(0);                      // chunk 3 landed (drain)
  COMPUTE(la0, lb0);

  // epilogue: negative-branch hinge only (mask handled by corr path)
  float lsum = 0.0f;
  #pragma unroll
  for (int i = 0; i < 5; ++i)
    #pragma unroll
    for (int j = 0; j < 3; ++j)
      #pragma unroll
      for (int q = 0; q < 4; ++q)
        lsum += fmaxf(acc[i][j][q] - M_NEG, 0.0f);

  #pragma unroll
  for (int off = 32; off > 0; off >>= 1)
    lsum += __shfl_xor(lsum, off);
  if (l == 0) red[w] = lsum;
  __syncthreads();
  if (tid == 0)
    gemmbuf[nb] = red[0] + red[1] + red[2] + red[3];
}

// ---------------- final reduction over all partials ----------------
__global__ void finalize_kernel(const float* __restrict__ parts, float* __restrict__ out) {
  float v = 0.0f;
  for (int i = threadIdx.x; i < NPART; i += 1024)
    v += parts[i];
  #pragma unroll
  for (int off = 32; off > 0; off >>= 1)
    v += __shfl_xor(v, off);
  __shared__ float red[16];
  if ((threadIdx.x & 63) == 0) red[threadIdx.x >> 6] = v;
  __syncthreads();
  if (threadIdx.x == 0) {
    float s = 0.0f;
    #pragma unroll
    for (int i = 0; i < 16; ++i) s += red[i];
    out[0] = s * (1.0f / ((float)NB * (float)NN * (float)NN));
  }
}

extern "C" void kernel_launch(void* const* d_in, const int* in_sizes, int n_in,
                              void* d_out, int out_size, void* d_ws, size_t ws_size,
                              hipStream_t stream) {
  const float* da = (const float*)d_in[0];
  const float* db = (const float*)d_in[1];
  const float* H  = (const float*)d_in[2];
  // d_in[3] = valid_mask (all ones, unused by the reference math)

  char* ws = (char*)d_ws;
  float* gemmbuf = (float*)ws;                    // 6000 floats
  float* corrbuf = (float*)(ws + CORR_OFF);       // 4800 floats, contiguous after
  unsigned char* A8 = (unsigned char*)(ws + A8_OFF);
  unsigned char* B8 = (unsigned char*)(ws + B8_OFF);

  t8_kernel<<<2400, 256, 0, stream>>>(da, db, A8, B8);
  fused_kernel<<<NGEMM + NCORR, 256, 0, stream>>>(A8, B8, H, gemmbuf, corrbuf);
  finalize_kernel<<<1, 1024, 0, stream>>>(gemmbuf, (float*)d_out);
}